// Round 1
// baseline (579.468 us; speedup 1.0000x reference)
//
#include <hip/hip_runtime.h>

#define DECAY 0.9f
#define INHIB 0.1f
#define TH_DEC 0.9f
#define TH_INC 0.1f

// Sizes (fixed by the problem)
#define BATCH 32
#define SEQ   1024
#define IDIM  512
#define ODIM  512

// ---------------- GEMM: proj[s][b][o] = sum_i x[b][s][i]*W[o][i] + bias[o] ----------------
// A = x viewed as [M=B*S][K] row-major (row r = b*SEQ + s), B = W [O][K] row-major.
// Output written in [S][B][O] layout so the scan reads contiguous 512-float rows.

#define BM 128
#define BN 128
#define BK 16

__global__ __launch_bounds__(256) void gemm_kernel(
    const float* __restrict__ X, const float* __restrict__ Wm,
    const float* __restrict__ bias, float* __restrict__ P)
{
    __shared__ float As[BK][BM];
    __shared__ float Bs[BK][BN];

    const int bm = blockIdx.x * BM;     // M block (rows of x)
    const int bn = blockIdx.y * BN;     // N block (output neurons)
    const int tid = threadIdx.x;        // 0..255

    // staging: each thread loads 8 floats of A and 8 of B per K-chunk
    const int row = tid >> 1;           // 0..127
    const int kq  = (tid & 1) * 8;      // 0 or 8

    // microtile mapping
    const int tx = tid & 15;            // N direction
    const int ty = tid >> 4;            // M direction

    float acc[8][8];
#pragma unroll
    for (int i = 0; i < 8; ++i)
#pragma unroll
        for (int j = 0; j < 8; ++j) acc[i][j] = 0.0f;

    const float* aPtr = X  + (size_t)(bm + row) * IDIM + kq;
    const float* bPtr = Wm + (size_t)(bn + row) * IDIM + kq;

    for (int k0 = 0; k0 < IDIM; k0 += BK) {
        float4 a0 = *(const float4*)(aPtr + k0);
        float4 a1 = *(const float4*)(aPtr + k0 + 4);
        float4 b0 = *(const float4*)(bPtr + k0);
        float4 b1 = *(const float4*)(bPtr + k0 + 4);

        __syncthreads();   // protect previous iteration's LDS reads
        As[kq+0][row] = a0.x; As[kq+1][row] = a0.y; As[kq+2][row] = a0.z; As[kq+3][row] = a0.w;
        As[kq+4][row] = a1.x; As[kq+5][row] = a1.y; As[kq+6][row] = a1.z; As[kq+7][row] = a1.w;
        Bs[kq+0][row] = b0.x; Bs[kq+1][row] = b0.y; Bs[kq+2][row] = b0.z; Bs[kq+3][row] = b0.w;
        Bs[kq+4][row] = b1.x; Bs[kq+5][row] = b1.y; Bs[kq+6][row] = b1.z; Bs[kq+7][row] = b1.w;
        __syncthreads();

#pragma unroll
        for (int kk = 0; kk < BK; ++kk) {
            float4 ar0 = *(const float4*)&As[kk][ty * 8];
            float4 ar1 = *(const float4*)&As[kk][ty * 8 + 4];
            float4 br0 = *(const float4*)&Bs[kk][tx * 8];
            float4 br1 = *(const float4*)&Bs[kk][tx * 8 + 4];
            float a_[8] = {ar0.x, ar0.y, ar0.z, ar0.w, ar1.x, ar1.y, ar1.z, ar1.w};
            float b_[8] = {br0.x, br0.y, br0.z, br0.w, br1.x, br1.y, br1.z, br1.w};
#pragma unroll
            for (int i = 0; i < 8; ++i)
#pragma unroll
                for (int j = 0; j < 8; ++j)
                    acc[i][j] += a_[i] * b_[j];
        }
    }

    float4 bi0 = *(const float4*)&bias[bn + tx * 8];
    float4 bi1 = *(const float4*)&bias[bn + tx * 8 + 4];
    const float bi[8] = {bi0.x, bi0.y, bi0.z, bi0.w, bi1.x, bi1.y, bi1.z, bi1.w};

#pragma unroll
    for (int i = 0; i < 8; ++i) {
        const int r  = bm + ty * 8 + i;     // r = b*SEQ + s
        const int bb = r >> 10;             // batch
        const int s  = r & (SEQ - 1);       // timestep
        float* dst = P + ((size_t)s * BATCH + bb) * ODIM + bn + tx * 8;
        float4 v0 = make_float4(acc[i][0] + bi[0], acc[i][1] + bi[1],
                                acc[i][2] + bi[2], acc[i][3] + bi[3]);
        float4 v1 = make_float4(acc[i][4] + bi[4], acc[i][5] + bi[5],
                                acc[i][6] + bi[6], acc[i][7] + bi[7]);
        *(float4*)dst       = v0;
        *(float4*)(dst + 4) = v1;
    }
}

// ---------------- Scan: sequential over S, one wave per batch ----------------
// Each lane owns 8 neurons: o = lane*4..lane*4+3 and 256+lane*4..+3.
// NOTE: the membrane reset MUST be the literal expression
//   mem = mem*(1-spike) + spike*(mem-thr)
// to reproduce IEEE inf*0=NaN semantics of the reference (post-overflow regime).

#define SDEPTH 4

__global__ __launch_bounds__(64) void scan_kernel(
    const float* __restrict__ P, float* __restrict__ Out)
{
    const int b    = blockIdx.x;    // 0..31
    const int lane = threadIdx.x;   // 0..63
    const size_t rowStride = (size_t)BATCH * ODIM;   // floats per timestep

    const float* p0 = P + (size_t)b * ODIM + lane * 4;
    const float* p1 = p0 + 256;
    float* o0 = Out + (size_t)b * SEQ * ODIM + lane * 4;
    float* o1 = o0 + 256;

    float4 mem0 = make_float4(0.f, 0.f, 0.f, 0.f);
    float4 mem1 = make_float4(0.f, 0.f, 0.f, 0.f);
    float4 thr0 = make_float4(1.f, 1.f, 1.f, 1.f);
    float4 thr1 = make_float4(1.f, 1.f, 1.f, 1.f);

    float4 buf0[SDEPTH], buf1[SDEPTH];
#pragma unroll
    for (int u = 0; u < SDEPTH; ++u) {
        buf0[u] = *(const float4*)(p0 + (size_t)u * rowStride);
        buf1[u] = *(const float4*)(p1 + (size_t)u * rowStride);
    }

#define UPD(m, t, pv, sp) {                         \
        float cur = (pv) - shift;                   \
        (m) = DECAY * (m) + cur;                    \
        float spike = ((m) >= (t)) ? 1.0f : 0.0f;   \
        (m) = (m) * (1.0f - spike) + spike * ((m) - (t)); \
        (t) = TH_DEC * (t) + TH_INC * spike;        \
        (sp) = spike; }

    for (int so = 0; so < SEQ; so += SDEPTH) {
#pragma unroll
        for (int u = 0; u < SDEPTH; ++u) {
            const int s = so + u;
            const float4 pa = buf0[u];
            const float4 pb = buf1[u];
            const int sn = s + SDEPTH;
            if (sn < SEQ) {   // prefetch SDEPTH steps ahead
                buf0[u] = *(const float4*)(p0 + (size_t)sn * rowStride);
                buf1[u] = *(const float4*)(p1 + (size_t)sn * rowStride);
            }

            // per-batch sum of mem across all 512 neurons
            float tot = ((mem0.x + mem0.y) + (mem0.z + mem0.w))
                      + ((mem1.x + mem1.y) + (mem1.z + mem1.w));
#pragma unroll
            for (int off = 32; off; off >>= 1)
                tot += __shfl_xor(tot, off, 64);

            const float shift = INHIB * tot;

            float4 sp0, sp1;
            UPD(mem0.x, thr0.x, pa.x, sp0.x);
            UPD(mem0.y, thr0.y, pa.y, sp0.y);
            UPD(mem0.z, thr0.z, pa.z, sp0.z);
            UPD(mem0.w, thr0.w, pa.w, sp0.w);
            UPD(mem1.x, thr1.x, pb.x, sp1.x);
            UPD(mem1.y, thr1.y, pb.y, sp1.y);
            UPD(mem1.z, thr1.z, pb.z, sp1.z);
            UPD(mem1.w, thr1.w, pb.w, sp1.w);

            *(float4*)(o0 + (size_t)s * ODIM) = sp0;
            *(float4*)(o1 + (size_t)s * ODIM) = sp1;
        }
    }
#undef UPD
}

extern "C" void kernel_launch(void* const* d_in, const int* in_sizes, int n_in,
                              void* d_out, int out_size, void* d_ws, size_t ws_size,
                              hipStream_t stream) {
    const float* x    = (const float*)d_in[0];   // [B, S, I]
    const float* W    = (const float*)d_in[1];   // [O, I]
    const float* bias = (const float*)d_in[2];   // [O]
    float* out  = (float*)d_out;                 // [B, S, O]
    float* proj = (float*)d_ws;                  // [S, B, O] scratch (64 MB)

    dim3 ggrid((BATCH * SEQ) / BM, ODIM / BN);   // 256 x 4
    gemm_kernel<<<ggrid, dim3(256), 0, stream>>>(x, W, bias, proj);
    scan_kernel<<<dim3(BATCH), dim3(64), 0, stream>>>(proj, out);
}

// Round 2
// 124.301 us; speedup vs baseline: 4.6618x; 4.6618x over previous
//
#include <hip/hip_runtime.h>

#define DECAY 0.9f
#define INHIB 0.1f
#define TH_DEC 0.9f
#define TH_INC 0.1f

// Fixed problem sizes
#define BATCH 32
#define SEQ   1024
#define IDIM  512
#define ODIM  512
#define SHEAD 128     // head phase covers s in [0, SHEAD)
#define SDEPTH 4

// ws layout: proj [SEQ][BATCH][ODIM] fp32 (64 MB, same as round 1).
// After scan_head consumes rows s=0,1 they are reused as a state stash:
//   proj[0][b][o] = saved mem   (only if batch alive at s=SHEAD)
//   proj[1][b][o] = saved thr;  proj[1][b][0] < 0 marks "batch dead, output done"
//   (thr is provably always > 0 and never NaN, so -1.0f is unambiguous)

// ================= GEMM head: proj[s][b][o], s in [0,SHEAD) =================
// grid (BATCH, ODIM/64), 256 threads. BM=128(s) x BN=64(o), BK=16, microtile 8x4.
__global__ __launch_bounds__(256) void gemm_head(
    const float* __restrict__ X, const float* __restrict__ Wm,
    const float* __restrict__ bias, float* __restrict__ P)
{
    __shared__ float As[16][128];
    __shared__ float Bs[16][64];

    const int b   = blockIdx.x;
    const int bn  = blockIdx.y * 64;
    const int tid = threadIdx.x;

    const int arow = tid >> 1, akq = (tid & 1) * 8;   // A stage: 8 floats/thread
    const int brow = tid >> 2, bkq = (tid & 3) * 4;   // B stage: 4 floats/thread
    const int tx = tid & 15, ty = tid >> 4;           // microtile 8(M) x 4(N)

    float acc[8][4];
#pragma unroll
    for (int i = 0; i < 8; ++i)
#pragma unroll
        for (int j = 0; j < 4; ++j) acc[i][j] = 0.0f;

    const float* aPtr = X  + ((size_t)b * SEQ + arow) * IDIM + akq;
    const float* bPtr = Wm + (size_t)(bn + brow) * IDIM + bkq;

    for (int k0 = 0; k0 < IDIM; k0 += 16) {
        float4 a0 = *(const float4*)(aPtr + k0);
        float4 a1 = *(const float4*)(aPtr + k0 + 4);
        float4 b0 = *(const float4*)(bPtr + k0);

        __syncthreads();
        As[akq+0][arow] = a0.x; As[akq+1][arow] = a0.y; As[akq+2][arow] = a0.z; As[akq+3][arow] = a0.w;
        As[akq+4][arow] = a1.x; As[akq+5][arow] = a1.y; As[akq+6][arow] = a1.z; As[akq+7][arow] = a1.w;
        Bs[bkq+0][brow] = b0.x; Bs[bkq+1][brow] = b0.y; Bs[bkq+2][brow] = b0.z; Bs[bkq+3][brow] = b0.w;
        __syncthreads();

#pragma unroll
        for (int kk = 0; kk < 16; ++kk) {
            float4 ar0 = *(const float4*)&As[kk][ty * 8];
            float4 ar1 = *(const float4*)&As[kk][ty * 8 + 4];
            float4 br  = *(const float4*)&Bs[kk][tx * 4];
            float a_[8] = {ar0.x, ar0.y, ar0.z, ar0.w, ar1.x, ar1.y, ar1.z, ar1.w};
            float b_[4] = {br.x, br.y, br.z, br.w};
#pragma unroll
            for (int i = 0; i < 8; ++i)
#pragma unroll
                for (int j = 0; j < 4; ++j)
                    acc[i][j] += a_[i] * b_[j];
        }
    }

    float4 bi = *(const float4*)&bias[bn + tx * 4];
#pragma unroll
    for (int i = 0; i < 8; ++i) {
        const int s = ty * 8 + i;
        float* dst = P + ((size_t)s * BATCH + b) * ODIM + bn + tx * 4;
        *(float4*)dst = make_float4(acc[i][0] + bi.x, acc[i][1] + bi.y,
                                    acc[i][2] + bi.z, acc[i][3] + bi.w);
    }
}

// ================= GEMM tail: proj[s][b][o], s in [SHEAD,SEQ) ===============
// grid (BATCH*7, ODIM/128), 256 threads. Round-1 128x128 tile. Early-returns
// when every batch is marked dead (bench-data fast path).
__global__ __launch_bounds__(256) void gemm_tail(
    const float* __restrict__ X, const float* __restrict__ Wm,
    const float* __restrict__ bias, float* __restrict__ P)
{
    {
        const int lane = threadIdx.x & 63;
        float v = -1.0f;
        if (lane < BATCH) v = P[(size_t)(BATCH + lane) * ODIM];  // thr stash / dead marker
        if (__ballot(v >= 0.0f) == 0ull) return;                 // nobody survived
    }

    __shared__ float As[16][128];
    __shared__ float Bs[16][128];

    const int batch = blockIdx.x / 7;
    const int tile  = blockIdx.x % 7;
    const int s0    = SHEAD + tile * 128;
    const int bn    = blockIdx.y * 128;
    const int tid   = threadIdx.x;

    const int row = tid >> 1, kq = (tid & 1) * 8;
    const int tx = tid & 15, ty = tid >> 4;

    float acc[8][8];
#pragma unroll
    for (int i = 0; i < 8; ++i)
#pragma unroll
        for (int j = 0; j < 8; ++j) acc[i][j] = 0.0f;

    const float* aPtr = X  + ((size_t)batch * SEQ + s0 + row) * IDIM + kq;
    const float* bPtr = Wm + (size_t)(bn + row) * IDIM + kq;

    for (int k0 = 0; k0 < IDIM; k0 += 16) {
        float4 a0 = *(const float4*)(aPtr + k0);
        float4 a1 = *(const float4*)(aPtr + k0 + 4);
        float4 b0 = *(const float4*)(bPtr + k0);
        float4 b1 = *(const float4*)(bPtr + k0 + 4);

        __syncthreads();
        As[kq+0][row] = a0.x; As[kq+1][row] = a0.y; As[kq+2][row] = a0.z; As[kq+3][row] = a0.w;
        As[kq+4][row] = a1.x; As[kq+5][row] = a1.y; As[kq+6][row] = a1.z; As[kq+7][row] = a1.w;
        Bs[kq+0][row] = b0.x; Bs[kq+1][row] = b0.y; Bs[kq+2][row] = b0.z; Bs[kq+3][row] = b0.w;
        Bs[kq+4][row] = b1.x; Bs[kq+5][row] = b1.y; Bs[kq+6][row] = b1.z; Bs[kq+7][row] = b1.w;
        __syncthreads();

#pragma unroll
        for (int kk = 0; kk < 16; ++kk) {
            float4 ar0 = *(const float4*)&As[kk][ty * 8];
            float4 ar1 = *(const float4*)&As[kk][ty * 8 + 4];
            float4 br0 = *(const float4*)&Bs[kk][tx * 8];
            float4 br1 = *(const float4*)&Bs[kk][tx * 8 + 4];
            float a_[8] = {ar0.x, ar0.y, ar0.z, ar0.w, ar1.x, ar1.y, ar1.z, ar1.w};
            float b_[8] = {br0.x, br0.y, br0.z, br0.w, br1.x, br1.y, br1.z, br1.w};
#pragma unroll
            for (int i = 0; i < 8; ++i)
#pragma unroll
                for (int j = 0; j < 8; ++j)
                    acc[i][j] += a_[i] * b_[j];
        }
    }

    float4 bi0 = *(const float4*)&bias[bn + tx * 8];
    float4 bi1 = *(const float4*)&bias[bn + tx * 8 + 4];
#pragma unroll
    for (int i = 0; i < 8; ++i) {
        const int s = s0 + ty * 8 + i;
        float* dst = P + ((size_t)s * BATCH + batch) * ODIM + bn + tx * 8;
        *(float4*)dst       = make_float4(acc[i][0] + bi0.x, acc[i][1] + bi0.y,
                                          acc[i][2] + bi0.z, acc[i][3] + bi0.w);
        *(float4*)(dst + 4) = make_float4(acc[i][4] + bi1.x, acc[i][5] + bi1.y,
                                          acc[i][6] + bi1.z, acc[i][7] + bi1.w);
    }
}

// ================= Scan =================
__device__ __forceinline__ void zero_tail(float* outB, int sd, int lane) {
    // fill out[b][sd..SEQ)[*] with 0.0f; (SEQ-sd)*128 float4's, stride 64 lanes
    float4 z = make_float4(0.f, 0.f, 0.f, 0.f);
    float4* p = (float4*)(outB + (size_t)sd * ODIM);
    const int n4 = (SEQ - sd) * (ODIM / 4);
    for (int i = lane; i < n4; i += 64) p[i] = z;
}

// NOTE: the membrane reset MUST remain the literal expression
//   mem = mem*(1-spike) + spike*(mem-thr)
// to reproduce IEEE inf*0=NaN semantics of the reference.
#define UPD(m, t, pv, sp) {                         \
        float cur = (pv) - shift;                   \
        (m) = DECAY * (m) + cur;                    \
        float spike = ((m) >= (t)) ? 1.0f : 0.0f;   \
        (m) = (m) * (1.0f - spike) + spike * ((m) - (t)); \
        (t) = TH_DEC * (t) + TH_INC * spike;        \
        (sp) = spike; }

__global__ __launch_bounds__(64) void scan_head(float* P, float* __restrict__ Out)
{
    const int b    = blockIdx.x;
    const int lane = threadIdx.x;
    const size_t rowStride = (size_t)BATCH * ODIM;

    const float* p0 = P + (size_t)b * ODIM + lane * 4;
    const float* p1 = p0 + 256;
    float* outB = Out + (size_t)b * SEQ * ODIM;
    float* o0 = outB + lane * 4;
    float* o1 = o0 + 256;

    float4 mem0 = make_float4(0.f, 0.f, 0.f, 0.f);
    float4 mem1 = make_float4(0.f, 0.f, 0.f, 0.f);
    float4 thr0 = make_float4(1.f, 1.f, 1.f, 1.f);
    float4 thr1 = make_float4(1.f, 1.f, 1.f, 1.f);

    float4 buf0[SDEPTH], buf1[SDEPTH];
#pragma unroll
    for (int u = 0; u < SDEPTH; ++u) {
        buf0[u] = *(const float4*)(p0 + (size_t)u * rowStride);
        buf1[u] = *(const float4*)(p1 + (size_t)u * rowStride);
    }

    for (int so = 0; so < SHEAD; so += SDEPTH) {
#pragma unroll
        for (int u = 0; u < SDEPTH; ++u) {
            const int s = so + u;
            const float4 pa = buf0[u];
            const float4 pb = buf1[u];
            const int sn = s + SDEPTH;
            if (sn < SHEAD) {
                buf0[u] = *(const float4*)(p0 + (size_t)sn * rowStride);
                buf1[u] = *(const float4*)(p1 + (size_t)sn * rowStride);
            }

            float tot = ((mem0.x + mem0.y) + (mem0.z + mem0.w))
                      + ((mem1.x + mem1.y) + (mem1.z + mem1.w));
#pragma unroll
            for (int off = 32; off; off >>= 1)
                tot += __shfl_xor(tot, off, 64);

            if (tot != tot) {                    // NaN: absorbing, all later spikes = 0
                zero_tail(outB, s, lane);
                if (lane == 0) P[(size_t)(BATCH + b) * ODIM] = -1.0f;   // dead marker
                return;
            }

            const float shift = INHIB * tot;
            float4 sp0, sp1;
            UPD(mem0.x, thr0.x, pa.x, sp0.x);
            UPD(mem0.y, thr0.y, pa.y, sp0.y);
            UPD(mem0.z, thr0.z, pa.z, sp0.z);
            UPD(mem0.w, thr0.w, pa.w, sp0.w);
            UPD(mem1.x, thr1.x, pb.x, sp1.x);
            UPD(mem1.y, thr1.y, pb.y, sp1.y);
            UPD(mem1.z, thr1.z, pb.z, sp1.z);
            UPD(mem1.w, thr1.w, pb.w, sp1.w);

            *(float4*)(o0 + (size_t)s * ODIM) = sp0;
            *(float4*)(o1 + (size_t)s * ODIM) = sp1;
        }
    }

    // alive at s=SHEAD: stash state into consumed proj rows 0 (mem) and 1 (thr)
    float* sm = P + (size_t)b * ODIM;
    float* st = P + (size_t)(BATCH + b) * ODIM;
    *(float4*)(sm + lane * 4)       = mem0;
    *(float4*)(sm + 256 + lane * 4) = mem1;
    *(float4*)(st + lane * 4)       = thr0;   // thr > 0 always => marks "alive"
    *(float4*)(st + 256 + lane * 4) = thr1;
}

__global__ __launch_bounds__(64) void scan_tail(float* P, float* __restrict__ Out)
{
    const int b    = blockIdx.x;
    const int lane = threadIdx.x;

    if (P[(size_t)(BATCH + b) * ODIM] < 0.0f) return;   // dead: output already complete

    const size_t rowStride = (size_t)BATCH * ODIM;
    const float* p0 = P + (size_t)b * ODIM + lane * 4;
    const float* p1 = p0 + 256;
    float* outB = Out + (size_t)b * SEQ * ODIM;
    float* o0 = outB + lane * 4;
    float* o1 = o0 + 256;

    const float* sm = P + (size_t)b * ODIM;
    const float* st = P + (size_t)(BATCH + b) * ODIM;
    float4 mem0 = *(const float4*)(sm + lane * 4);
    float4 mem1 = *(const float4*)(sm + 256 + lane * 4);
    float4 thr0 = *(const float4*)(st + lane * 4);
    float4 thr1 = *(const float4*)(st + 256 + lane * 4);

    float4 buf0[SDEPTH], buf1[SDEPTH];
#pragma unroll
    for (int u = 0; u < SDEPTH; ++u) {
        buf0[u] = *(const float4*)(p0 + (size_t)(SHEAD + u) * rowStride);
        buf1[u] = *(const float4*)(p1 + (size_t)(SHEAD + u) * rowStride);
    }

    for (int so = SHEAD; so < SEQ; so += SDEPTH) {
#pragma unroll
        for (int u = 0; u < SDEPTH; ++u) {
            const int s = so + u;
            const float4 pa = buf0[u];
            const float4 pb = buf1[u];
            const int sn = s + SDEPTH;
            if (sn < SEQ) {
                buf0[u] = *(const float4*)(p0 + (size_t)sn * rowStride);
                buf1[u] = *(const float4*)(p1 + (size_t)sn * rowStride);
            }

            float tot = ((mem0.x + mem0.y) + (mem0.z + mem0.w))
                      + ((mem1.x + mem1.y) + (mem1.z + mem1.w));
#pragma unroll
            for (int off = 32; off; off >>= 1)
                tot += __shfl_xor(tot, off, 64);

            if (tot != tot) {
                zero_tail(outB, s, lane);
                return;
            }

            const float shift = INHIB * tot;
            float4 sp0, sp1;
            UPD(mem0.x, thr0.x, pa.x, sp0.x);
            UPD(mem0.y, thr0.y, pa.y, sp0.y);
            UPD(mem0.z, thr0.z, pa.z, sp0.z);
            UPD(mem0.w, thr0.w, pa.w, sp0.w);
            UPD(mem1.x, thr1.x, pb.x, sp1.x);
            UPD(mem1.y, thr1.y, pb.y, sp1.y);
            UPD(mem1.z, thr1.z, pb.z, sp1.z);
            UPD(mem1.w, thr1.w, pb.w, sp1.w);

            *(float4*)(o0 + (size_t)s * ODIM) = sp0;
            *(float4*)(o1 + (size_t)s * ODIM) = sp1;
        }
    }
}
#undef UPD

extern "C" void kernel_launch(void* const* d_in, const int* in_sizes, int n_in,
                              void* d_out, int out_size, void* d_ws, size_t ws_size,
                              hipStream_t stream) {
    const float* x    = (const float*)d_in[0];   // [B, S, I]
    const float* W    = (const float*)d_in[1];   // [O, I]
    const float* bias = (const float*)d_in[2];   // [O]
    float* out  = (float*)d_out;                 // [B, S, O]
    float* proj = (float*)d_ws;                  // [S, B, O] scratch (64 MB)

    gemm_head<<<dim3(BATCH, ODIM / 64), dim3(256), 0, stream>>>(x, W, bias, proj);
    scan_head<<<dim3(BATCH), dim3(64), 0, stream>>>(proj, out);
    gemm_tail<<<dim3(BATCH * ((SEQ - SHEAD) / 128), ODIM / 128), dim3(256), 0, stream>>>(x, W, bias, proj);
    scan_tail<<<dim3(BATCH), dim3(64), 0, stream>>>(proj, out);
}

// Round 3
// 45.371 us; speedup vs baseline: 12.7718x; 2.7397x over previous
//
#include <hip/hip_runtime.h>

#define DECAY 0.9f
#define INHIB 0.1f
#define TH_DEC 0.9f
#define TH_INC 0.1f

// Fixed problem sizes
#define BATCH 32
#define SEQ   1024
#define IDIM  512
#define ODIM  512
#define SHEAD 64      // head phase covers s in [0, SHEAD); batches die at s~25
#define SDEPTH 4

// ws layout: proj [SEQ][BATCH][ODIM] fp32 (64 MB).
// After scan_head consumes rows s=0,1 they are reused as a state stash:
//   proj[0][b][o] = saved mem   (only if batch alive at s=SHEAD)
//   proj[1][b][o] = saved thr;  proj[1][b][0] < 0 marks "batch dead, output done"
//   (thr is provably always > 0 and never NaN, so -1.0f is unambiguous)

// ---------------- DPP wave64 sum (VALU-only, ~6x4cy chain vs 6x120cy bpermute) ----
template <int CTRL>
__device__ __forceinline__ float dpp_add(float x) {
    int v = __builtin_amdgcn_update_dpp(0, __float_as_int(x), CTRL, 0xf, 0xf, true);
    return x + __int_as_float(v);
}
__device__ __forceinline__ float wave_sum_bcast(float x) {
    x = dpp_add<0x111>(x);   // row_shr:1
    x = dpp_add<0x112>(x);   // row_shr:2
    x = dpp_add<0x114>(x);   // row_shr:4
    x = dpp_add<0x118>(x);   // row_shr:8  -> lane 15+16k holds row-k sum
    x = dpp_add<0x142>(x);   // row_bcast:15
    x = dpp_add<0x143>(x);   // row_bcast:31 -> lane 63 holds wave total
    return __int_as_float(__builtin_amdgcn_readlane(__float_as_int(x), 63));
}

// ================= GEMM head + output pre-zero =================
// grid (BATCH, ODIM/64), 256 threads. Tile 64(s) x 64(o), BK=16, microtile 4x4.
// Also zeroes the ENTIRE output (paced stores) so scan kernels never bulk-fill.
__global__ __launch_bounds__(256) void gemm_head(
    const float* __restrict__ X, const float* __restrict__ Wm,
    const float* __restrict__ bias, float* __restrict__ P,
    float* __restrict__ Out)
{
    __shared__ float As[16][64];
    __shared__ float Bs[16][64];

    const int b   = blockIdx.x;
    const int bn  = blockIdx.y * 64;
    const int tid = threadIdx.x;

    const int srow = tid >> 2;          // 0..63
    const int skq  = (tid & 3) * 4;     // 0,4,8,12
    const int tx = tid & 15, ty = tid >> 4;   // microtile 4(M) x 4(N)

    // output zero-fill slab: contiguous 16384 float4 per block, 64 per thread
    const int blin = blockIdx.y * BATCH + blockIdx.x;    // 0..255
    float4* zp = (float4*)Out + (size_t)blin * 16384 + tid;
    const float4 zf4 = make_float4(0.f, 0.f, 0.f, 0.f);

    float acc[4][4];
#pragma unroll
    for (int i = 0; i < 4; ++i)
#pragma unroll
        for (int j = 0; j < 4; ++j) acc[i][j] = 0.0f;

    const float* aPtr = X  + ((size_t)b * SEQ + srow) * IDIM + skq;
    const float* bPtr = Wm + (size_t)(bn + srow) * IDIM + skq;

    float4 a  = *(const float4*)aPtr;
    float4 bb = *(const float4*)bPtr;
    int zi = 0;

    for (int k0 = 0; k0 < IDIM; k0 += 16) {
        __syncthreads();   // previous inner loop done reading LDS
        As[skq+0][srow] = a.x;  As[skq+1][srow] = a.y;
        As[skq+2][srow] = a.z;  As[skq+3][srow] = a.w;
        Bs[skq+0][srow] = bb.x; Bs[skq+1][srow] = bb.y;
        Bs[skq+2][srow] = bb.z; Bs[skq+3][srow] = bb.w;

        if (k0 + 16 < IDIM) {               // register prefetch of next K-tile
            a  = *(const float4*)(aPtr + k0 + 16);
            bb = *(const float4*)(bPtr + k0 + 16);
        }
        // paced zero stores (2/iter x 32 iters = 64 = whole slab), drain under FMA
        zp[(size_t)zi * 256] = zf4;
        zp[(size_t)(zi + 1) * 256] = zf4;
        zi += 2;
        __syncthreads();

#pragma unroll
        for (int kk = 0; kk < 16; ++kk) {
            float4 ar = *(const float4*)&As[kk][ty * 4];
            float4 br = *(const float4*)&Bs[kk][tx * 4];
            float a_[4] = {ar.x, ar.y, ar.z, ar.w};
            float b_[4] = {br.x, br.y, br.z, br.w};
#pragma unroll
            for (int i = 0; i < 4; ++i)
#pragma unroll
                for (int j = 0; j < 4; ++j)
                    acc[i][j] += a_[i] * b_[j];
        }
    }

    float4 bi = *(const float4*)&bias[bn + tx * 4];
#pragma unroll
    for (int i = 0; i < 4; ++i) {
        const int s = ty * 4 + i;
        float* dst = P + ((size_t)s * BATCH + b) * ODIM + bn + tx * 4;
        *(float4*)dst = make_float4(acc[i][0] + bi.x, acc[i][1] + bi.y,
                                    acc[i][2] + bi.z, acc[i][3] + bi.w);
    }
}

// ================= GEMM tail: proj[s][b][o], s in [SHEAD,SEQ) ===============
// grid (BATCH, ODIM/64), 256 threads, loops 15 s-tiles of 64. Correctness
// fallback only: early-outs when every batch is marked dead.
__global__ __launch_bounds__(256) void gemm_tail(
    const float* __restrict__ X, const float* __restrict__ Wm,
    const float* __restrict__ bias, float* __restrict__ P)
{
    {
        const int lane = threadIdx.x & 63;
        float v = -1.0f;
        if (lane < BATCH) v = P[(size_t)(BATCH + lane) * ODIM];  // thr stash / dead marker
        if (__ballot(v >= 0.0f) == 0ull) return;                 // nobody survived
    }

    __shared__ float As[16][64];
    __shared__ float Bs[16][64];

    const int b   = blockIdx.x;
    const int bn  = blockIdx.y * 64;
    const int tid = threadIdx.x;
    const int srow = tid >> 2, skq = (tid & 3) * 4;
    const int tx = tid & 15, ty = tid >> 4;

    const float* bPtr = Wm + (size_t)(bn + srow) * IDIM + skq;

    for (int st = 0; st < (SEQ - SHEAD) / 64; ++st) {
        const int s0 = SHEAD + st * 64;
        const float* aPtr = X + ((size_t)b * SEQ + s0 + srow) * IDIM + skq;

        float acc[4][4];
#pragma unroll
        for (int i = 0; i < 4; ++i)
#pragma unroll
            for (int j = 0; j < 4; ++j) acc[i][j] = 0.0f;

        for (int k0 = 0; k0 < IDIM; k0 += 16) {
            float4 a  = *(const float4*)(aPtr + k0);
            float4 bb = *(const float4*)(bPtr + k0);
            __syncthreads();
            As[skq+0][srow] = a.x;  As[skq+1][srow] = a.y;
            As[skq+2][srow] = a.z;  As[skq+3][srow] = a.w;
            Bs[skq+0][srow] = bb.x; Bs[skq+1][srow] = bb.y;
            Bs[skq+2][srow] = bb.z; Bs[skq+3][srow] = bb.w;
            __syncthreads();
#pragma unroll
            for (int kk = 0; kk < 16; ++kk) {
                float4 ar = *(const float4*)&As[kk][ty * 4];
                float4 br = *(const float4*)&Bs[kk][tx * 4];
                float a_[4] = {ar.x, ar.y, ar.z, ar.w};
                float b_[4] = {br.x, br.y, br.z, br.w};
#pragma unroll
                for (int i = 0; i < 4; ++i)
#pragma unroll
                    for (int j = 0; j < 4; ++j)
                        acc[i][j] += a_[i] * b_[j];
            }
        }

        float4 bi = *(const float4*)&bias[bn + tx * 4];
#pragma unroll
        for (int i = 0; i < 4; ++i) {
            const int s = s0 + ty * 4 + i;
            float* dst = P + ((size_t)s * BATCH + b) * ODIM + bn + tx * 4;
            *(float4*)dst = make_float4(acc[i][0] + bi.x, acc[i][1] + bi.y,
                                        acc[i][2] + bi.z, acc[i][3] + bi.w);
        }
    }
}

// ================= Scan =================
// NOTE: the membrane reset MUST remain the literal expression
//   mem = mem*(1-spike) + spike*(mem-thr)
// to reproduce IEEE inf*0=NaN semantics of the reference (posts NaN after the
// +-inf step; NaN sum is then an absorbing all-zero-spikes state).
#define UPD(m, t, pv, sp) {                         \
        float cur = (pv) - shift;                   \
        (m) = DECAY * (m) + cur;                    \
        float spike = ((m) >= (t)) ? 1.0f : 0.0f;   \
        (m) = (m) * (1.0f - spike) + spike * ((m) - (t)); \
        (t) = TH_DEC * (t) + TH_INC * spike;        \
        (sp) = spike; }

__global__ __launch_bounds__(64) void scan_head(float* P, float* __restrict__ Out)
{
    const int b    = blockIdx.x;
    const int lane = threadIdx.x;
    const size_t rowStride = (size_t)BATCH * ODIM;

    const float* p0 = P + (size_t)b * ODIM + lane * 4;
    const float* p1 = p0 + 256;
    float* o0 = Out + (size_t)b * SEQ * ODIM + lane * 4;
    float* o1 = o0 + 256;

    float4 mem0 = make_float4(0.f, 0.f, 0.f, 0.f);
    float4 mem1 = make_float4(0.f, 0.f, 0.f, 0.f);
    float4 thr0 = make_float4(1.f, 1.f, 1.f, 1.f);
    float4 thr1 = make_float4(1.f, 1.f, 1.f, 1.f);

    float4 buf0[SDEPTH], buf1[SDEPTH];
#pragma unroll
    for (int u = 0; u < SDEPTH; ++u) {
        buf0[u] = *(const float4*)(p0 + (size_t)u * rowStride);
        buf1[u] = *(const float4*)(p1 + (size_t)u * rowStride);
    }

    for (int so = 0; so < SHEAD; so += SDEPTH) {
#pragma unroll
        for (int u = 0; u < SDEPTH; ++u) {
            const int s = so + u;
            const float4 pa = buf0[u];
            const float4 pb = buf1[u];
            const int sn = s + SDEPTH;
            if (sn < SHEAD) {
                buf0[u] = *(const float4*)(p0 + (size_t)sn * rowStride);
                buf1[u] = *(const float4*)(p1 + (size_t)sn * rowStride);
            }

            float part = ((mem0.x + mem0.y) + (mem0.z + mem0.w))
                       + ((mem1.x + mem1.y) + (mem1.z + mem1.w));
            const float tot = wave_sum_bcast(part);

            if (tot != tot) {   // NaN: absorbing, tail already pre-zeroed by gemm_head
                if (lane == 0) P[(size_t)(BATCH + b) * ODIM] = -1.0f;   // dead marker
                return;
            }

            const float shift = INHIB * tot;
            float4 sp0, sp1;
            UPD(mem0.x, thr0.x, pa.x, sp0.x);
            UPD(mem0.y, thr0.y, pa.y, sp0.y);
            UPD(mem0.z, thr0.z, pa.z, sp0.z);
            UPD(mem0.w, thr0.w, pa.w, sp0.w);
            UPD(mem1.x, thr1.x, pb.x, sp1.x);
            UPD(mem1.y, thr1.y, pb.y, sp1.y);
            UPD(mem1.z, thr1.z, pb.z, sp1.z);
            UPD(mem1.w, thr1.w, pb.w, sp1.w);

            *(float4*)(o0 + (size_t)s * ODIM) = sp0;
            *(float4*)(o1 + (size_t)s * ODIM) = sp1;
        }
    }

    // alive at s=SHEAD: stash state into consumed proj rows 0 (mem) and 1 (thr)
    float* sm = P + (size_t)b * ODIM;
    float* st = P + (size_t)(BATCH + b) * ODIM;
    *(float4*)(sm + lane * 4)       = mem0;
    *(float4*)(sm + 256 + lane * 4) = mem1;
    *(float4*)(st + lane * 4)       = thr0;   // thr > 0 always => marks "alive"
    *(float4*)(st + 256 + lane * 4) = thr1;
}

__global__ __launch_bounds__(64) void scan_tail(float* P, float* __restrict__ Out)
{
    const int b    = blockIdx.x;
    const int lane = threadIdx.x;

    if (P[(size_t)(BATCH + b) * ODIM] < 0.0f) return;   // dead: output already complete

    const size_t rowStride = (size_t)BATCH * ODIM;
    const float* p0 = P + (size_t)b * ODIM + lane * 4;
    const float* p1 = p0 + 256;
    float* o0 = Out + (size_t)b * SEQ * ODIM + lane * 4;
    float* o1 = o0 + 256;

    const float* sm = P + (size_t)b * ODIM;
    const float* st = P + (size_t)(BATCH + b) * ODIM;
    float4 mem0 = *(const float4*)(sm + lane * 4);
    float4 mem1 = *(const float4*)(sm + 256 + lane * 4);
    float4 thr0 = *(const float4*)(st + lane * 4);
    float4 thr1 = *(const float4*)(st + 256 + lane * 4);

    float4 buf0[SDEPTH], buf1[SDEPTH];
#pragma unroll
    for (int u = 0; u < SDEPTH; ++u) {
        buf0[u] = *(const float4*)(p0 + (size_t)(SHEAD + u) * rowStride);
        buf1[u] = *(const float4*)(p1 + (size_t)(SHEAD + u) * rowStride);
    }

    for (int so = SHEAD; so < SEQ; so += SDEPTH) {
#pragma unroll
        for (int u = 0; u < SDEPTH; ++u) {
            const int s = so + u;
            const float4 pa = buf0[u];
            const float4 pb = buf1[u];
            const int sn = s + SDEPTH;
            if (sn < SEQ) {
                buf0[u] = *(const float4*)(p0 + (size_t)sn * rowStride);
                buf1[u] = *(const float4*)(p1 + (size_t)sn * rowStride);
            }

            float part = ((mem0.x + mem0.y) + (mem0.z + mem0.w))
                       + ((mem1.x + mem1.y) + (mem1.z + mem1.w));
            const float tot = wave_sum_bcast(part);

            if (tot != tot) return;   // tail already pre-zeroed

            const float shift = INHIB * tot;
            float4 sp0, sp1;
            UPD(mem0.x, thr0.x, pa.x, sp0.x);
            UPD(mem0.y, thr0.y, pa.y, sp0.y);
            UPD(mem0.z, thr0.z, pa.z, sp0.z);
            UPD(mem0.w, thr0.w, pa.w, sp0.w);
            UPD(mem1.x, thr1.x, pb.x, sp1.x);
            UPD(mem1.y, thr1.y, pb.y, sp1.y);
            UPD(mem1.z, thr1.z, pb.z, sp1.z);
            UPD(mem1.w, thr1.w, pb.w, sp1.w);

            *(float4*)(o0 + (size_t)s * ODIM) = sp0;
            *(float4*)(o1 + (size_t)s * ODIM) = sp1;
        }
    }
}
#undef UPD

extern "C" void kernel_launch(void* const* d_in, const int* in_sizes, int n_in,
                              void* d_out, int out_size, void* d_ws, size_t ws_size,
                              hipStream_t stream) {
    const float* x    = (const float*)d_in[0];   // [B, S, I]
    const float* W    = (const float*)d_in[1];   // [O, I]
    const float* bias = (const float*)d_in[2];   // [O]
    float* out  = (float*)d_out;                 // [B, S, O]
    float* proj = (float*)d_ws;                  // [S, B, O] scratch (64 MB)

    gemm_head<<<dim3(BATCH, ODIM / 64), dim3(256), 0, stream>>>(x, W, bias, proj, out);
    scan_head<<<dim3(BATCH), dim3(64), 0, stream>>>(proj, out);
    gemm_tail<<<dim3(BATCH, ODIM / 64), dim3(256), 0, stream>>>(x, W, bias, proj);
    scan_tail<<<dim3(BATCH), dim3(64), 0, stream>>>(proj, out);
}